// Round 1
// baseline (144.015 us; speedup 1.0000x reference)
//
#include <hip/hip_runtime.h>
#include <hip/hip_bf16.h>

// Problem constants
#define B_  1024
#define LA  529   // token positions -> conv channels
#define EE  100   // embedding dim -> conv steps
#define NF  16    // conv filters
#define NT  50    // conv output steps (stride 2, SAME => no pad)
#define NS  25    // pooled steps
#define NU  100   // LSTM units
#define NJ  400   // 4*NU
#define CHUNK 64
#define NBB 4     // batches per block in kernel B

__device__ __forceinline__ float leaky(float v) {
    return v >= 0.f ? v : 0.2f * v;
}

// ---------------- Kernel A: gather + conv + relu + maxpool ----------------
// one block per batch element; output p[b][s][f]  (B x 25 x 16)
__global__ __launch_bounds__(256) void conv_embed_kernel(
    const int*   __restrict__ tokens,
    const float* __restrict__ emb,
    const float* __restrict__ conv_w,   // [2][529][16]
    const float* __restrict__ conv_b,   // [16]
    float*       __restrict__ p_out)    // [B][25][16]
{
    __shared__ int tok_lds[LA];
    __shared__ __align__(16) float emb_lds[CHUNK][EE];
    __shared__ __align__(16) float cw0_lds[CHUNK][NF];
    __shared__ __align__(16) float cw1_lds[CHUNK][NF];
    __shared__ __align__(16) float y_lds[NT][NF];

    const int b   = blockIdx.x;
    const int tid = threadIdx.x;

    for (int i = tid; i < LA; i += 256) tok_lds[i] = tokens[b * LA + i];
    __syncthreads();

    const int t  = tid >> 2;   // 0..49 valid when tid < 200
    const int fg = tid & 3;    // f quad
    float4 acc = make_float4(0.f, 0.f, 0.f, 0.f);

    for (int c0 = 0; c0 < LA; c0 += CHUNK) {
        const int cnt = min(CHUNK, LA - c0);
        // stage emb rows for this chunk of token positions (float4 loads)
        for (int idx = tid; idx < cnt * 25; idx += 256) {
            const int r = idx / 25, pos = idx % 25;
            float4 v = ((const float4*)(emb + (size_t)tok_lds[c0 + r] * EE))[pos];
            ((float4*)emb_lds[r])[pos] = v;
        }
        // stage conv weights for this chunk (w=0 and w=1 planes)
        for (int idx = tid; idx < cnt * 4; idx += 256) {
            const int r = idx >> 2, q = idx & 3;
            ((float4*)cw0_lds[r])[q] = ((const float4*)(conv_w + (size_t)(c0 + r) * NF))[q];
            ((float4*)cw1_lds[r])[q] = ((const float4*)(conv_w + (size_t)(LA + c0 + r) * NF))[q];
        }
        __syncthreads();

        if (tid < 200) {
            for (int cp = 0; cp < cnt; ++cp) {
                float2 e  = ((const float2*)emb_lds[cp])[t];   // emb[., 2t], emb[., 2t+1]
                float4 w0 = ((const float4*)cw0_lds[cp])[fg];
                float4 w1 = ((const float4*)cw1_lds[cp])[fg];
                acc.x += e.x * w0.x + e.y * w1.x;
                acc.y += e.x * w0.y + e.y * w1.y;
                acc.z += e.x * w0.z + e.y * w1.z;
                acc.w += e.x * w0.w + e.y * w1.w;
            }
        }
        __syncthreads();
    }

    if (tid < 200) {
        float4 cb = ((const float4*)conv_b)[fg];
        y_lds[t][fg * 4 + 0] = fmaxf(acc.x + cb.x, 0.f);
        y_lds[t][fg * 4 + 1] = fmaxf(acc.y + cb.y, 0.f);
        y_lds[t][fg * 4 + 2] = fmaxf(acc.z + cb.z, 0.f);
        y_lds[t][fg * 4 + 3] = fmaxf(acc.w + cb.w, 0.f);
    }
    __syncthreads();

    // maxpool k=2 s=2 over steps -> [25][16], write to global
    for (int idx = tid; idx < NS * NF; idx += 256) {
        const int s = idx >> 4, f = idx & 15;
        p_out[b * (NS * NF) + idx] = fmaxf(y_lds[2 * s][f], y_lds[2 * s + 1][f]);
    }
}

// ---------------- Kernel B: LSTM scan + dense head + softmax ----------------
// one block per NBB=4 batch rows; 448 threads (7 waves).
// threads 0..399 each own one z-column j (rk column in registers);
// threads 0..399 also own (b,u) pairs for the gate/cell update.
__global__ __launch_bounds__(448) void lstm_head_kernel(
    const float* __restrict__ p_in,    // [B][25][16]
    const float* __restrict__ k_lstm,  // [16][400]
    const float* __restrict__ rk,      // [100][400]
    const float* __restrict__ b_lstm,  // [400]
    const float* __restrict__ w1,      // [100][64]
    const float* __restrict__ b1,      // [64]
    const float* __restrict__ w2,      // [64][3]
    const float* __restrict__ b2,      // [3]
    float*       __restrict__ out)     // [B][3]
{
    __shared__ __align__(16) float p_lds[NBB][NS][NF];
    __shared__ __align__(16) float h_lds[NBB][NU];
    __shared__ float z_lds[NBB][NJ];
    __shared__ float d_lds[NBB * 64];

    const int tid = threadIdx.x;
    const int b0  = blockIdx.x * NBB;

    for (int idx = tid; idx < NBB * NS * NF; idx += 448)
        ((float*)p_lds)[idx] = p_in[b0 * (NS * NF) + idx];
    for (int idx = tid; idx < NBB * NU; idx += 448)
        ((float*)h_lds)[idx] = 0.f;

    float rk_reg[NU];
    float kl_reg[NF];
    float blv = 0.f;
    if (tid < NJ) {
#pragma unroll
        for (int k = 0; k < NU; ++k) rk_reg[k] = rk[k * NJ + tid];
#pragma unroll
        for (int f = 0; f < NF; ++f) kl_reg[f] = k_lstm[f * NJ + tid];
        blv = b_lstm[tid];
    }
    float c_reg = 0.f;
    const int ub = tid / NU;   // batch for gate update (tid < 400)
    const int uu = tid % NU;   // unit  for gate update
    __syncthreads();

#pragma unroll 1
    for (int t = 0; t < NS; ++t) {
        if (tid < NJ) {
            float a0 = blv, a1 = blv, a2 = blv, a3 = blv;
            // input projection: z += p[b][t][:] . k_lstm[:, j]
#pragma unroll
            for (int q = 0; q < 4; ++q) {
                float4 p0 = ((const float4*)p_lds[0][t])[q];
                float4 p1 = ((const float4*)p_lds[1][t])[q];
                float4 p2 = ((const float4*)p_lds[2][t])[q];
                float4 p3 = ((const float4*)p_lds[3][t])[q];
                const float k0 = kl_reg[4 * q + 0], k1 = kl_reg[4 * q + 1];
                const float k2 = kl_reg[4 * q + 2], k3 = kl_reg[4 * q + 3];
                a0 += p0.x * k0 + p0.y * k1 + p0.z * k2 + p0.w * k3;
                a1 += p1.x * k0 + p1.y * k1 + p1.z * k2 + p1.w * k3;
                a2 += p2.x * k0 + p2.y * k1 + p2.z * k2 + p2.w * k3;
                a3 += p3.x * k0 + p3.y * k1 + p3.z * k2 + p3.w * k3;
            }
            // recurrent projection: z += h[b][:] . rk[:, j]
#pragma unroll
            for (int k4 = 0; k4 < NU / 4; ++k4) {
                float4 h0 = ((const float4*)h_lds[0])[k4];
                float4 h1 = ((const float4*)h_lds[1])[k4];
                float4 h2 = ((const float4*)h_lds[2])[k4];
                float4 h3 = ((const float4*)h_lds[3])[k4];
                const float r0 = rk_reg[4 * k4 + 0], r1 = rk_reg[4 * k4 + 1];
                const float r2 = rk_reg[4 * k4 + 2], r3 = rk_reg[4 * k4 + 3];
                a0 += h0.x * r0 + h0.y * r1 + h0.z * r2 + h0.w * r3;
                a1 += h1.x * r0 + h1.y * r1 + h1.z * r2 + h1.w * r3;
                a2 += h2.x * r0 + h2.y * r1 + h2.z * r2 + h2.w * r3;
                a3 += h3.x * r0 + h3.y * r1 + h3.z * r2 + h3.w * r3;
            }
            z_lds[0][tid] = a0;
            z_lds[1][tid] = a1;
            z_lds[2][tid] = a2;
            z_lds[3][tid] = a3;
        }
        __syncthreads();
        if (tid < NBB * NU) {
            const float zi = z_lds[ub][uu];
            const float zf = z_lds[ub][NU + uu];
            const float zg = z_lds[ub][2 * NU + uu];
            const float zo = z_lds[ub][3 * NU + uu];
            const float ig  = 1.f / (1.f + expf(-zi));
            const float fg_ = 1.f / (1.f + expf(-zf));
            const float og  = 1.f / (1.f + expf(-zo));
            c_reg = fg_ * c_reg + ig * leaky(zg);
            h_lds[ub][uu] = og * leaky(c_reg);
        }
        __syncthreads();
    }

    // dense head: d = tanh(h @ w1 + b1)
    if (tid < NBB * 64) {
        const int hb = tid >> 6, m = tid & 63;
        float a = b1[m];
#pragma unroll
        for (int u = 0; u < NU; ++u) a += h_lds[hb][u] * w1[u * 64 + m];
        d_lds[tid] = tanhf(a);
    }
    __syncthreads();

    // logits + softmax (3 classes)
    if (tid < NBB) {
        float l0 = b2[0], l1 = b2[1], l2 = b2[2];
        for (int m = 0; m < 64; ++m) {
            const float d = d_lds[tid * 64 + m];
            l0 += d * w2[m * 3 + 0];
            l1 += d * w2[m * 3 + 1];
            l2 += d * w2[m * 3 + 2];
        }
        const float mx = fmaxf(l0, fmaxf(l1, l2));
        const float e0 = expf(l0 - mx), e1 = expf(l1 - mx), e2 = expf(l2 - mx);
        const float inv = 1.f / (e0 + e1 + e2);
        out[(b0 + tid) * 3 + 0] = e0 * inv;
        out[(b0 + tid) * 3 + 1] = e1 * inv;
        out[(b0 + tid) * 3 + 2] = e2 * inv;
    }
}

extern "C" void kernel_launch(void* const* d_in, const int* in_sizes, int n_in,
                              void* d_out, int out_size, void* d_ws, size_t ws_size,
                              hipStream_t stream) {
    const int*   tokens = (const int*)  d_in[0];
    const float* emb    = (const float*)d_in[1];
    const float* conv_w = (const float*)d_in[2];
    const float* conv_b = (const float*)d_in[3];
    const float* k_lstm = (const float*)d_in[4];
    const float* rk     = (const float*)d_in[5];
    const float* b_lstm = (const float*)d_in[6];
    const float* w1     = (const float*)d_in[7];
    const float* b1     = (const float*)d_in[8];
    const float* w2     = (const float*)d_in[9];
    const float* b2     = (const float*)d_in[10];
    float* out  = (float*)d_out;
    float* p_ws = (float*)d_ws;   // [B][25][16] = 1.6 MB

    conv_embed_kernel<<<B_, 256, 0, stream>>>(tokens, emb, conv_w, conv_b, p_ws);
    lstm_head_kernel<<<B_ / NBB, 448, 0, stream>>>(p_ws, k_lstm, rk, b_lstm,
                                                   w1, b1, w2, b2, out);
}